// Round 4
// baseline (533.054 us; speedup 1.0000x reference)
//
#include <hip/hip_runtime.h>
#include <stdint.h>

#define BETA 0.9f
#define NIN 784
#define KA0 832            // 784 padded to multiple of 32
#define NHID 2048
#define BATCH 128
#define TSTEPS 32
#define MROWS 4096         // 32*128

typedef __bf16 bf16x8 __attribute__((ext_vector_type(8)));
typedef float f32x4 __attribute__((ext_vector_type(4)));

// ---------- helpers ----------
__device__ __forceinline__ unsigned short f2bf_rne(float f) {
  union { float f; unsigned u; } v; v.f = f;
  unsigned u = v.u;
  return (unsigned short)((u + 0x7FFFu + ((u >> 16) & 1u)) >> 16);
}
__device__ __forceinline__ float bf2f(unsigned short b) {
  union { unsigned u; float f; } v; v.u = ((unsigned)b) << 16;
  return v.f;
}
__device__ __forceinline__ float nofuse(float x) {  // block fp-contraction
  asm volatile("" : "+v"(x));
  return x;
}

typedef __attribute__((address_space(1))) const unsigned int gas_uint;
typedef __attribute__((address_space(3))) unsigned int las_uint;
__device__ __forceinline__ void gload_lds16(const void* g, void* l) {
  __builtin_amdgcn_global_load_lds((gas_uint*)g, (las_uint*)l, 16, 0, 0);
}

// ---------- ws layout (CUR2 appended at END so fallback path keeps old offsets) ----------
static const size_t SZ_WS0  = (size_t)3 * 2048 * KA0 * 2;    // W0 hi/mid/lo
static const size_t SZ_WSH  = (size_t)3 * 2048 * 2048 * 2;   // W1..W3
static const size_t SZ_W4T  = (size_t)2048 * 16 * 4;
static const size_t SZ_SPK  = (size_t)MROWS * 2048 * 2;
static const size_t SZ_CUR  = (size_t)MROWS * 2048 * 4;
static const size_t SZ_CUR5 = (size_t)MROWS * 16 * 4;
static const size_t SZ_VST  = (size_t)5 * TSTEPS * 256 * 2 * 4;
static const size_t SZ_CST  = (size_t)6 * TSTEPS * 256 * 4;

static const size_t OFF_WS0  = 0;
static const size_t OFF_WS1  = OFF_WS0 + SZ_WS0;
static const size_t OFF_WS2  = OFF_WS1 + SZ_WSH;
static const size_t OFF_WS3  = OFF_WS2 + SZ_WSH;
static const size_t OFF_W4T  = OFF_WS3 + SZ_WSH;
static const size_t OFF_SPKA = OFF_W4T + SZ_W4T;
static const size_t OFF_SPKB = OFF_SPKA + SZ_SPK;
static const size_t OFF_CUR  = OFF_SPKB + SZ_SPK;
static const size_t OFF_CUR5 = OFF_CUR + SZ_CUR;
static const size_t OFF_VST  = OFF_CUR5 + SZ_CUR5;
static const size_t OFF_CST  = OFF_VST + SZ_VST;
static const size_t OFF_CUR2 = OFF_CST + SZ_CST;             // split-K z=1 partials
static const size_t WS_NEED_SPLIT = OFF_CUR2 + SZ_CUR;

// ---------- prep: split fp32 W into hi/mid/lo bf16 planes ----------
__global__ void k_wsplit(const float* __restrict__ W, unsigned short* __restrict__ dst,
                         int nrows, int kvalid, int kpad) {
  int idx = blockIdx.x * blockDim.x + threadIdx.x;
  int kq = kvalid >> 2;
  if (idx >= nrows * kq) return;
  int row = idx / kq, k0 = (idx - row * kq) * 4;
  const float* src = W + (size_t)row * kvalid + k0;
  unsigned short h[4], m[4], l[4];
#pragma unroll
  for (int e = 0; e < 4; ++e) {
    float f = src[e];
    unsigned short hb = f2bf_rne(f);
    float r1 = f - bf2f(hb);
    unsigned short mb = f2bf_rne(r1);
    float r2 = r1 - bf2f(mb);
    unsigned short lb = f2bf_rne(r2);
    h[e] = hb; m[e] = mb; l[e] = lb;
  }
  size_t base = (size_t)row * kpad + k0;
  size_t plane = (size_t)nrows * kpad;
  *(ushort4*)(dst + base)             = make_ushort4(h[0], h[1], h[2], h[3]);
  *(ushort4*)(dst + plane + base)     = make_ushort4(m[0], m[1], m[2], m[3]);
  *(ushort4*)(dst + 2 * plane + base) = make_ushort4(l[0], l[1], l[2], l[3]);
}

__global__ void k_w4t(const float* __restrict__ W4, float* __restrict__ w4t) {
  int k = blockIdx.x * blockDim.x + threadIdx.x;
  if (k >= 2048) return;
#pragma unroll
  for (int c = 0; c < 16; ++c)
    w4t[(size_t)k * 16 + c] = (c < 10) ? W4[(size_t)c * 2048 + k] : 0.f;
}

// =====================================================================
// NEW main GEMM (phase-interleaved, counted-vmcnt, split-K x2)
// BM=256 BN=128 BK=32, 256 thr, 4 waves (2m x 2n), per-wave 128x64.
// LDS: dbuf x 40KB (A 16KB + 3xB 8KB) = 80KB -> 2 blocks/CU = 160KB exactly.
// Per K-step: head {vmcnt(0); s_barrier} is the ONLY correctness sync
// (reads buf p, all gloads write p^1). 3 plane-phases, each
// {gload-issue || ds_read; s_barrier; setprio(1); 32 MFMA; setprio(0)}.
// grid 512 = 16m x 16n... (16 m-tiles x 16 n-tiles x 2 z) XCD-swizzled.
// =====================================================================
__global__ __launch_bounds__(256, 2) void k_gemm3p(
    const unsigned short* __restrict__ A,   // [M][Ka] bf16 bits
    const unsigned short* __restrict__ B,   // [3][N][Ka] bf16 bits (W rows)
    float* __restrict__ C0,                 // z=0 partials [M][N]
    float* __restrict__ C1,                 // z=1 partials [M][N]
    int N, int Ka) {
  __shared__ unsigned short smem[2][20480]; // per buf: A[0,8192) | B s*4096 (128x32 each)
  const int tid = threadIdx.x;
  const int lane = tid & 63, wv = tid >> 6;

  // XCD swizzle: 512 blocks -> xcd gets 2 m-tiles x 16 n x 2 z (A slice L2-resident)
  const int bid = blockIdx.x;
  const int xcd = bid & 7, lid = bid >> 3;           // lid 0..63
  const int mt = xcd * 2 + (lid >> 5);               // 0..15
  const int nt = (lid >> 1) & 15;                    // 0..15
  const int z  = lid & 1;
  const int m0 = mt * 256, n0 = nt * 128;
  const int Kh = Ka >> 1;                            // split-K half
  const int NT = Kh >> 5;
  const int koff0 = z * Kh;

  f32x4 acc[8][4];
#pragma unroll
  for (int i = 0; i < 8; ++i)
#pragma unroll
    for (int j = 0; j < 4; ++j) acc[i][j] = (f32x4){0.f, 0.f, 0.f, 0.f};

  // stage chunks i0..i1-1 of K-step kt into buf (10 chunks total per thread)
  auto stage_range = [&](int buf, int kt, int i0, int i1) {
    const int koff = koff0 + kt * 32;
    const unsigned short* Abase = A + (size_t)m0 * Ka + koff;
    for (int i = i0; i < i1; ++i) {
      int c = i * 256 + tid;
      const unsigned short* src;
      if (c < 1024) {                        // A: 256 rows x 32k
        int row = c >> 2, kb = c & 3;
        int gkb = kb ^ ((row >> 1) & 3);     // source pre-swizzle (rule #21)
        src = Abase + (size_t)row * Ka + gkb * 8;
      } else {                               // B planes: 3 x (128 rows x 32k)
        int cb = c - 1024;
        int s = cb >> 9, cc = cb & 511;
        int row = cc >> 2, kb = cc & 3;
        int gkb = kb ^ ((row >> 1) & 3);
        src = B + ((size_t)s * N + n0 + row) * Ka + koff + gkb * 8;
      }
      gload_lds16(src, &smem[buf][(i * 256 + wv * 64) * 8]);
    }
  };

  const int wm = wv >> 1, wn = wv & 1;
  const int g = lane >> 4, rr = lane & 15;

  // prologue: stage step 0 fully
  stage_range(0, 0, 0, 10);

  for (int kt = 0; kt < NT; ++kt) {
    const int p = kt & 1;
    const bool pf = (kt + 1 < NT);
    // ---- step head: ONLY correctness-critical sync ----
    asm volatile("s_waitcnt vmcnt(0)" ::: "memory");
    __builtin_amdgcn_sched_barrier(0);
    __builtin_amdgcn_s_barrier();
    __builtin_amdgcn_sched_barrier(0);

    bf16x8 a[8];
    // ---- phase 0: A-frags + plane0, stage chunks 0..3 ----
    if (pf) stage_range(p ^ 1, kt + 1, 0, 4);
#pragma unroll
    for (int mf = 0; mf < 8; ++mf) {
      int row = wm * 128 + mf * 16 + rr;
      int slot = g ^ ((row >> 1) & 3);
      a[mf] = *(const bf16x8*)&smem[p][row * 32 + slot * 8];
    }
    {
      bf16x8 b[4];
#pragma unroll
      for (int nf = 0; nf < 4; ++nf) {
        int row = wn * 64 + nf * 16 + rr;
        int slot = g ^ ((row >> 1) & 3);
        b[nf] = *(const bf16x8*)&smem[p][8192 + row * 32 + slot * 8];
      }
      __builtin_amdgcn_s_barrier();
      __builtin_amdgcn_sched_barrier(0);
      __builtin_amdgcn_s_setprio(1);
#pragma unroll
      for (int mf = 0; mf < 8; ++mf)
#pragma unroll
        for (int nf = 0; nf < 4; ++nf)
          acc[mf][nf] = __builtin_amdgcn_mfma_f32_16x16x32_bf16(a[mf], b[nf], acc[mf][nf], 0, 0, 0);
      __builtin_amdgcn_s_setprio(0);
    }
    // ---- phase 1: plane1, stage chunks 4..6 ----
    if (pf) stage_range(p ^ 1, kt + 1, 4, 7);
    {
      bf16x8 b[4];
#pragma unroll
      for (int nf = 0; nf < 4; ++nf) {
        int row = wn * 64 + nf * 16 + rr;
        int slot = g ^ ((row >> 1) & 3);
        b[nf] = *(const bf16x8*)&smem[p][8192 + 4096 + row * 32 + slot * 8];
      }
      __builtin_amdgcn_s_barrier();
      __builtin_amdgcn_sched_barrier(0);
      __builtin_amdgcn_s_setprio(1);
#pragma unroll
      for (int mf = 0; mf < 8; ++mf)
#pragma unroll
        for (int nf = 0; nf < 4; ++nf)
          acc[mf][nf] = __builtin_amdgcn_mfma_f32_16x16x32_bf16(a[mf], b[nf], acc[mf][nf], 0, 0, 0);
      __builtin_amdgcn_s_setprio(0);
    }
    // ---- phase 2: plane2, stage chunks 7..9 ----
    if (pf) stage_range(p ^ 1, kt + 1, 7, 10);
    {
      bf16x8 b[4];
#pragma unroll
      for (int nf = 0; nf < 4; ++nf) {
        int row = wn * 64 + nf * 16 + rr;
        int slot = g ^ ((row >> 1) & 3);
        b[nf] = *(const bf16x8*)&smem[p][8192 + 8192 + row * 32 + slot * 8];
      }
      __builtin_amdgcn_s_barrier();
      __builtin_amdgcn_sched_barrier(0);
      __builtin_amdgcn_s_setprio(1);
#pragma unroll
      for (int mf = 0; mf < 8; ++mf)
#pragma unroll
        for (int nf = 0; nf < 4; ++nf)
          acc[mf][nf] = __builtin_amdgcn_mfma_f32_16x16x32_bf16(a[mf], b[nf], acc[mf][nf], 0, 0, 0);
      __builtin_amdgcn_s_setprio(0);
    }
  }

  float* __restrict__ Cz = z ? C1 : C0;
#pragma unroll
  for (int mf = 0; mf < 8; ++mf)
#pragma unroll
    for (int nf = 0; nf < 4; ++nf) {
      int col = n0 + wn * 64 + nf * 16 + rr;
#pragma unroll
      for (int v = 0; v < 4; ++v) {
        int row = m0 + wm * 128 + mf * 16 + g * 4 + v;  // D: row=(lane>>4)*4+reg, col=lane&15
        Cz[(size_t)row * N + col] = acc[mf][nf][v];
      }
    }
}

// ---------- fallback GEMM (round-3 proven path, used if ws too small) ----------
__global__ __launch_bounds__(256) void k_gemm3_old(
    const unsigned short* __restrict__ A, const unsigned short* __restrict__ B,
    float* __restrict__ C, int N, int Ka) {
  __shared__ unsigned short smem[2][16384];
  const int tid = threadIdx.x;
  const int lane = tid & 63, wv = tid >> 6;
  const int bid = blockIdx.x;
  const int xcd = bid & 7, lid = bid >> 3;
  const int by = (xcd >> 1) * 8 + (lid >> 3);
  const int bx = (xcd & 1) * 8 + (lid & 7);
  const int m0 = by * 128, n0 = bx * 128;
  const int NT = Ka >> 5;
  f32x4 acc[4][4];
#pragma unroll
  for (int i = 0; i < 4; ++i)
#pragma unroll
    for (int j = 0; j < 4; ++j) acc[i][j] = (f32x4){0.f, 0.f, 0.f, 0.f};
  auto stage = [&](int buf, int kk) {
    const unsigned short* Ab = A + (size_t)m0 * Ka + (size_t)kk * 32;
    const unsigned short* Bb = B + (size_t)n0 * Ka + (size_t)kk * 32;
#pragma unroll
    for (int i = 0; i < 8; ++i) {
      int chunk = wv * 64 + lane + i * 256;
      const unsigned short* src;
      if (i < 2) {
        int row = chunk >> 2, kb = chunk & 3;
        int gkb = kb ^ ((row >> 1) & 3);
        src = Ab + (size_t)row * Ka + gkb * 8;
      } else {
        int cb = chunk - 512;
        int s = cb >> 9, cc = cb & 511;
        int row = cc >> 2, kb = cc & 3;
        int gkb = kb ^ ((row >> 1) & 3);
        src = Bb + ((size_t)s * N + row) * Ka + gkb * 8;
      }
      gload_lds16(src, &smem[buf][i * 2048 + wv * 512]);
    }
  };
  const int wm = wv >> 1, wn = wv & 1;
  const int g = lane >> 4, rr = lane & 15;
  auto compute = [&](int buf) {
    bf16x8 a[4];
#pragma unroll
    for (int mf = 0; mf < 4; ++mf) {
      int row = wm * 64 + mf * 16 + rr;
      int slot = g ^ ((row >> 1) & 3);
      a[mf] = *(const bf16x8*)&smem[buf][row * 32 + slot * 8];
    }
#pragma unroll
    for (int s = 0; s < 3; ++s) {
      bf16x8 b[4];
#pragma unroll
      for (int nf = 0; nf < 4; ++nf) {
        int row = wn * 64 + nf * 16 + rr;
        int slot = g ^ ((row >> 1) & 3);
        b[nf] = *(const bf16x8*)&smem[buf][4096 + s * 4096 + row * 32 + slot * 8];
      }
#pragma unroll
      for (int mf = 0; mf < 4; ++mf)
#pragma unroll
        for (int nf = 0; nf < 4; ++nf)
          acc[mf][nf] = __builtin_amdgcn_mfma_f32_16x16x32_bf16(a[mf], b[nf], acc[mf][nf], 0, 0, 0);
    }
  };
  stage(0, 0);
  __syncthreads();
  for (int kt = 0; kt < NT; ++kt) {
    if (kt + 1 < NT) stage((kt + 1) & 1, kt + 1);
    compute(kt & 1);
    __syncthreads();
  }
#pragma unroll
  for (int mf = 0; mf < 4; ++mf)
#pragma unroll
    for (int nf = 0; nf < 4; ++nf) {
      int col = n0 + wn * 64 + nf * 16 + rr;
#pragma unroll
      for (int v = 0; v < 4; ++v) {
        int row = m0 + wm * 64 + mf * 16 + g * 4 + v;
        C[(size_t)row * N + col] = acc[mf][nf][v];
      }
    }
}

// ---------- LIF scans ----------
__global__ __launch_bounds__(128) void k_scan0(
    const float* __restrict__ input, unsigned short* __restrict__ spk0,
    float* __restrict__ vstats, int* __restrict__ cstats) {
  const int b = blockIdx.x, tid = threadIdx.x;
  const int j0 = tid * 8;
  const bool act = (j0 < NIN);
  const int lane = tid & 63, wv = tid >> 6;
  __shared__ float ssum[2][TSTEPS], ssq[2][TSTEPS];
  __shared__ int scnt[2][TSTEPS];
  float iv[8];
  if (act) {
    const float* ip = input + (size_t)b * NIN + j0;
    float4 c0 = *(const float4*)ip, c1 = *(const float4*)(ip + 4);
    iv[0]=c0.x; iv[1]=c0.y; iv[2]=c0.z; iv[3]=c0.w;
    iv[4]=c1.x; iv[5]=c1.y; iv[6]=c1.z; iv[7]=c1.w;
  } else {
#pragma unroll
    for (int e = 0; e < 8; ++e) iv[e] = 0.f;
  }
  float mem[8] = {0,0,0,0,0,0,0,0};
  for (int t = 0; t < TSTEPS; ++t) {
    float sum = 0.f, sq = 0.f; int cnt = 0;
    unsigned short sb[8];
#pragma unroll
    for (int e = 0; e < 8; ++e) {
      float reset = mem[e] > 1.0f ? 1.0f : 0.0f;
      float t1 = nofuse(BETA * mem[e]);
      float t2 = nofuse(t1 + iv[e]);
      float mn = t2 - reset;
      mem[e] = mn;
      int s = mn > 1.0f;
      sb[e] = s ? (unsigned short)0x3F80 : (unsigned short)0;
      sum += mn; sq = __fmaf_rn(mn, mn, sq); cnt += s;
    }
    if (act) {
      unsigned short* op = spk0 + (size_t)(t * BATCH + b) * KA0 + j0;
      *(ushort4*)op       = make_ushort4(sb[0], sb[1], sb[2], sb[3]);
      *(ushort4*)(op + 4) = make_ushort4(sb[4], sb[5], sb[6], sb[7]);
    }
#pragma unroll
    for (int o = 32; o > 0; o >>= 1) {
      sum += __shfl_down(sum, o, 64);
      sq  += __shfl_down(sq, o, 64);
      cnt += __shfl_down(cnt, o, 64);
    }
    if (lane == 0) { ssum[wv][t] = sum; ssq[wv][t] = sq; scnt[wv][t] = cnt; }
  }
  __syncthreads();
  if (tid < TSTEPS) {
    int t = tid;
    float s = ssum[0][t] + ssum[1][t];
    float q = ssq[0][t] + ssq[1][t];
    int c = scnt[0][t] + scnt[1][t];
    vstats[((size_t)(0 * TSTEPS + t) * 256 + b) * 2 + 0] = s;
    vstats[((size_t)(0 * TSTEPS + t) * 256 + b) * 2 + 1] = q;
    cstats[(0 * TSTEPS + t) * 256 + b] = c;
  }
}

// layers 1..4: cur = cur0 (+cur1 if parts==2) + bias -> LIF -> spk bf16
__global__ __launch_bounds__(128) void k_scan(
    const float* __restrict__ cur0, const float* __restrict__ cur1,
    const float* __restrict__ bias,
    unsigned short* __restrict__ spk, float* __restrict__ vstats,
    int* __restrict__ cstats, int layer, int parts) {
  const int blk = blockIdx.x;
  const int b = blk >> 1, half = blk & 1;
  const int tid = threadIdx.x;
  const int j0 = half * 1024 + tid * 8;
  const int lane = tid & 63, wv = tid >> 6;
  __shared__ float ssum[2][TSTEPS], ssq[2][TSTEPS];
  __shared__ int scnt[2][TSTEPS];
  float bs[8];
  {
    const float* bp = bias + j0;
    float4 c0 = *(const float4*)bp, c1 = *(const float4*)(bp + 4);
    bs[0]=c0.x; bs[1]=c0.y; bs[2]=c0.z; bs[3]=c0.w;
    bs[4]=c1.x; bs[5]=c1.y; bs[6]=c1.z; bs[7]=c1.w;
  }
  float mem[8] = {0,0,0,0,0,0,0,0};
  for (int t = 0; t < TSTEPS; ++t) {
    size_t off = (size_t)(t * BATCH + b) * 2048 + j0;
    const float* cp = cur0 + off;
    float4 c0 = *(const float4*)cp, c1 = *(const float4*)(cp + 4);
    float cv[8] = {c0.x, c0.y, c0.z, c0.w, c1.x, c1.y, c1.z, c1.w};
    if (parts == 2) {
      const float* cq = cur1 + off;
      float4 d0 = *(const float4*)cq, d1 = *(const float4*)(cq + 4);
      float dv[8] = {d0.x, d0.y, d0.z, d0.w, d1.x, d1.y, d1.z, d1.w};
#pragma unroll
      for (int e = 0; e < 8; ++e) cv[e] = nofuse(cv[e] + dv[e]);
    }
    float sum = 0.f, sq = 0.f; int cnt = 0;
    unsigned short sb[8];
#pragma unroll
    for (int e = 0; e < 8; ++e) {
      float cc = nofuse(cv[e] + bs[e]);
      float reset = mem[e] > 1.0f ? 1.0f : 0.0f;
      float t1 = nofuse(BETA * mem[e]);
      float t2 = nofuse(t1 + cc);
      float mn = t2 - reset;
      mem[e] = mn;
      int s = mn > 1.0f;
      sb[e] = s ? (unsigned short)0x3F80 : (unsigned short)0;
      sum += mn; sq = __fmaf_rn(mn, mn, sq); cnt += s;
    }
    unsigned short* op = spk + (size_t)(t * BATCH + b) * 2048 + j0;
    *(ushort4*)op       = make_ushort4(sb[0], sb[1], sb[2], sb[3]);
    *(ushort4*)(op + 4) = make_ushort4(sb[4], sb[5], sb[6], sb[7]);
#pragma unroll
    for (int o = 32; o > 0; o >>= 1) {
      sum += __shfl_down(sum, o, 64);
      sq  += __shfl_down(sq, o, 64);
      cnt += __shfl_down(cnt, o, 64);
    }
    if (lane == 0) { ssum[wv][t] = sum; ssq[wv][t] = sq; scnt[wv][t] = cnt; }
  }
  __syncthreads();
  if (tid < TSTEPS) {
    int t = tid;
    float s = ssum[0][t] + ssum[1][t];
    float q = ssq[0][t] + ssq[1][t];
    int c = scnt[0][t] + scnt[1][t];
    vstats[((size_t)(layer * TSTEPS + t) * 256 + blk) * 2 + 0] = s;
    vstats[((size_t)(layer * TSTEPS + t) * 256 + blk) * 2 + 1] = q;
    cstats[(layer * TSTEPS + t) * 256 + blk] = c;
  }
}

// small final GEMM: cur5[4096x16] = spk4 * W4t (fp32, exact per-dot fma)
__global__ __launch_bounds__(256) void k_gemm4(
    const unsigned short* __restrict__ spk, const float* __restrict__ w4t,
    float* __restrict__ out) {
  int idx = blockIdx.x * 256 + threadIdx.x;
  int r = idx >> 4, c = idx & 15;
  const unsigned short* sp = spk + (size_t)r * 2048;
  float acc = 0.f;
  for (int k = 0; k < 2048; k += 4) {
    ushort4 s4 = *(const ushort4*)(sp + k);
    acc = __fmaf_rn(bf2f(s4.x), w4t[(size_t)(k + 0) * 16 + c], acc);
    acc = __fmaf_rn(bf2f(s4.y), w4t[(size_t)(k + 1) * 16 + c], acc);
    acc = __fmaf_rn(bf2f(s4.z), w4t[(size_t)(k + 2) * 16 + c], acc);
    acc = __fmaf_rn(bf2f(s4.w), w4t[(size_t)(k + 3) * 16 + c], acc);
  }
  out[(size_t)r * 16 + c] = acc;
}

// layer 5: LIF over cur5, writes spike_out (d_out+5), counts only
__global__ __launch_bounds__(640) void k_scan5(
    const float* __restrict__ cur5, const float* __restrict__ b4,
    float* __restrict__ spike_out, int* __restrict__ cstats) {
  const int tid = threadIdx.x;
  const int idx = blockIdx.x * 640 + tid;
  const int b = idx / 10, j = idx - b * 10;
  const int lane = tid & 63, wv = tid >> 6;
  __shared__ int scnt[10][TSTEPS];
  const float bias = b4[j];
  float mem = 0.f;
  for (int t = 0; t < TSTEPS; ++t) {
    float cc = nofuse(cur5[(size_t)(t * BATCH + b) * 16 + j] + bias);
    float reset = mem > 1.0f ? 1.0f : 0.0f;
    float t1 = nofuse(BETA * mem);
    float t2 = nofuse(t1 + cc);
    float mn = t2 - reset;
    mem = mn;
    int s = mn > 1.0f;
    spike_out[(size_t)t * 1280 + b * 10 + j] = s ? 1.0f : 0.0f;
    int cnt = s;
#pragma unroll
    for (int o = 32; o > 0; o >>= 1) cnt += __shfl_down(cnt, o, 64);
    if (lane == 0) scnt[wv][t] = cnt;
  }
  __syncthreads();
  if (tid < TSTEPS) {
    int t = tid, c = 0;
#pragma unroll
    for (int w = 0; w < 10; ++w) c += scnt[w][t];
    cstats[(5 * TSTEPS + t) * 256 + blockIdx.x] = c;
  }
}

// final reduction
__global__ __launch_bounds__(512) void k_final(
    const float* __restrict__ vstats, const int* __restrict__ cstats,
    float* __restrict__ d_out) {
  __shared__ float varLDS[5][TSTEPS];
  __shared__ float cntLDS[6][TSTEPS];
  int tid = threadIdx.x;
  if (tid < 160) {
    int l = tid / 32, t = tid - l * 32;
    double s = 0.0, q = 0.0;
    for (int b = 0; b < 256; ++b) {
      s += (double)vstats[((size_t)(l * TSTEPS + t) * 256 + b) * 2 + 0];
      q += (double)vstats[((size_t)(l * TSTEPS + t) * 256 + b) * 2 + 1];
    }
    double n = (l == 0) ? (double)(BATCH * NIN) : (double)(BATCH * NHID);
    varLDS[l][t] = (float)((q - s * s / n) / (n - 1.0));
  } else if (tid < 352) {
    int i = (tid - 160) / 32, t = (tid - 160) - i * 32;
    int c = 0;
    for (int b = 0; b < 256; ++b) c += cstats[(i * TSTEPS + t) * 256 + b];
    cntLDS[i][t] = (float)c * (1.0f / 128.0f);
  }
  __syncthreads();
  if (tid < 5) {
    float a = 0.f;
    for (int t = 0; t < TSTEPS; ++t) a = __fadd_rn(a, varLDS[tid][t]);
    d_out[tid] = a / 32.0f;
  } else if (tid >= 8 && tid < 14) {
    int i = tid - 8;
    float a = 0.f;
    for (int t = 0; t < TSTEPS; ++t) a = __fadd_rn(a, cntLDS[i][t]);
    d_out[40965 + i] = a / 4096.0f;
  }
}

// ---------- launch ----------
extern "C" void kernel_launch(void* const* d_in, const int* in_sizes, int n_in,
                              void* d_out, int out_size, void* d_ws, size_t ws_size,
                              hipStream_t stream) {
  const float* input = (const float*)d_in[0];
  const float* W0 = (const float*)d_in[1];
  const float* W1 = (const float*)d_in[2];
  const float* W2 = (const float*)d_in[3];
  const float* W3 = (const float*)d_in[4];
  const float* W4 = (const float*)d_in[5];
  const float* b0 = (const float*)d_in[6];
  const float* b1 = (const float*)d_in[7];
  const float* b2 = (const float*)d_in[8];
  const float* b3 = (const float*)d_in[9];
  const float* b4 = (const float*)d_in[10];

  uint8_t* ws = (uint8_t*)d_ws;
  unsigned short* ws0  = (unsigned short*)(ws + OFF_WS0);
  unsigned short* ws1  = (unsigned short*)(ws + OFF_WS1);
  unsigned short* ws2  = (unsigned short*)(ws + OFF_WS2);
  unsigned short* ws3  = (unsigned short*)(ws + OFF_WS3);
  float* w4t           = (float*)(ws + OFF_W4T);
  unsigned short* spkA = (unsigned short*)(ws + OFF_SPKA);
  unsigned short* spkB = (unsigned short*)(ws + OFF_SPKB);
  float* cur           = (float*)(ws + OFF_CUR);
  float* cur2          = (float*)(ws + OFF_CUR2);
  float* cur5          = (float*)(ws + OFF_CUR5);
  float* vst           = (float*)(ws + OFF_VST);
  int* cst             = (int*)(ws + OFF_CST);
  float* out           = (float*)d_out;

  const bool split = (ws_size >= WS_NEED_SPLIT);

  hipMemsetAsync(ws + OFF_VST, 0, SZ_VST + SZ_CST, stream);
  hipMemsetAsync(ws + OFF_SPKA, 0, (size_t)TSTEPS * BATCH * KA0 * 2, stream);
  hipMemsetAsync(ws + OFF_WS0, 0, SZ_WS0, stream);

  {
    int thr = 2048 * (NIN / 4);
    k_wsplit<<<(thr + 255) / 256, 256, 0, stream>>>(W0, ws0, 2048, NIN, KA0);
  }
  {
    int thr = 2048 * (2048 / 4);
    int gb = (thr + 255) / 256;
    k_wsplit<<<gb, 256, 0, stream>>>(W1, ws1, 2048, 2048, 2048);
    k_wsplit<<<gb, 256, 0, stream>>>(W2, ws2, 2048, 2048, 2048);
    k_wsplit<<<gb, 256, 0, stream>>>(W3, ws3, 2048, 2048, 2048);
  }
  k_w4t<<<8, 256, 0, stream>>>(W4, w4t);

  k_scan0<<<BATCH, 128, 0, stream>>>(input, spkA, vst, cst);
  if (split) {
    k_gemm3p<<<512, 256, 0, stream>>>(spkA, ws0, cur, cur2, 2048, KA0);
    k_scan<<<256, 128, 0, stream>>>(cur, cur2, b0, spkB, vst, cst, 1, 2);
    k_gemm3p<<<512, 256, 0, stream>>>(spkB, ws1, cur, cur2, 2048, 2048);
    k_scan<<<256, 128, 0, stream>>>(cur, cur2, b1, spkA, vst, cst, 2, 2);
    k_gemm3p<<<512, 256, 0, stream>>>(spkA, ws2, cur, cur2, 2048, 2048);
    k_scan<<<256, 128, 0, stream>>>(cur, cur2, b2, spkB, vst, cst, 3, 2);
    k_gemm3p<<<512, 256, 0, stream>>>(spkB, ws3, cur, cur2, 2048, 2048);
    k_scan<<<256, 128, 0, stream>>>(cur, cur2, b3, spkA, vst, cst, 4, 2);
  } else {
    k_gemm3_old<<<512, 256, 0, stream>>>(spkA, ws0, cur, 2048, KA0);
    k_scan<<<256, 128, 0, stream>>>(cur, cur, b0, spkB, vst, cst, 1, 1);
    k_gemm3_old<<<512, 256, 0, stream>>>(spkB, ws1, cur, 2048, 2048);
    k_scan<<<256, 128, 0, stream>>>(cur, cur, b1, spkA, vst, cst, 2, 1);
    k_gemm3_old<<<512, 256, 0, stream>>>(spkA, ws2, cur, 2048, 2048);
    k_scan<<<256, 128, 0, stream>>>(cur, cur, b2, spkB, vst, cst, 3, 1);
    k_gemm3_old<<<512, 256, 0, stream>>>(spkB, ws3, cur, 2048, 2048);
    k_scan<<<256, 128, 0, stream>>>(cur, cur, b3, spkA, vst, cst, 4, 1);
  }
  k_gemm4<<<256, 256, 0, stream>>>(spkA, w4t, cur5);
  k_scan5<<<2, 640, 0, stream>>>(cur5, b4, out + 5, cst);
  k_final<<<1, 512, 0, stream>>>(vst, cst, out);
}

// Round 5
// 491.644 us; speedup vs baseline: 1.0842x; 1.0842x over previous
//
#include <hip/hip_runtime.h>
#include <stdint.h>

#define BETA 0.9f
#define NIN 784
#define KA0 832            // 784 padded to multiple of 32
#define NHID 2048
#define BATCH 128
#define TSTEPS 32
#define MROWS 4096         // 32*128

typedef __bf16 bf16x8 __attribute__((ext_vector_type(8)));
typedef float f32x4 __attribute__((ext_vector_type(4)));

// ---------- helpers ----------
__device__ __forceinline__ unsigned short f2bf_rne(float f) {
  union { float f; unsigned u; } v; v.f = f;
  unsigned u = v.u;
  return (unsigned short)((u + 0x7FFFu + ((u >> 16) & 1u)) >> 16);
}
__device__ __forceinline__ float bf2f(unsigned short b) {
  union { unsigned u; float f; } v; v.u = ((unsigned)b) << 16;
  return v.f;
}
__device__ __forceinline__ float nofuse(float x) {  // block fp-contraction
  asm volatile("" : "+v"(x));
  return x;
}

typedef __attribute__((address_space(1))) const unsigned int gas_uint;
typedef __attribute__((address_space(3))) unsigned int las_uint;
__device__ __forceinline__ void gload_lds16(const void* g, void* l) {
  __builtin_amdgcn_global_load_lds((gas_uint*)g, (las_uint*)l, 16, 0, 0);
}

// ---------- ws layout ----------
static const size_t SZ_WS0  = (size_t)3 * 2048 * KA0 * 2;    // W0 hi/mid/lo
static const size_t SZ_WSH  = (size_t)3 * 2048 * 2048 * 2;   // W1..W3
static const size_t SZ_W4T  = (size_t)2048 * 16 * 4;
static const size_t SZ_SPK  = (size_t)MROWS * 2048 * 2;
static const size_t SZ_CUR  = (size_t)MROWS * 2048 * 4;
static const size_t SZ_CUR5 = (size_t)MROWS * 16 * 4;
static const size_t SZ_VST  = (size_t)5 * TSTEPS * 256 * 2 * 4;
static const size_t SZ_CST  = (size_t)6 * TSTEPS * 256 * 4;

static const size_t OFF_WS0  = 0;
static const size_t OFF_WS1  = OFF_WS0 + SZ_WS0;
static const size_t OFF_WS2  = OFF_WS1 + SZ_WSH;
static const size_t OFF_WS3  = OFF_WS2 + SZ_WSH;
static const size_t OFF_W4T  = OFF_WS3 + SZ_WSH;
static const size_t OFF_SPKA = OFF_W4T + SZ_W4T;
static const size_t OFF_SPKB = OFF_SPKA + SZ_SPK;
static const size_t OFF_CUR  = OFF_SPKB + SZ_SPK;
static const size_t OFF_CUR5 = OFF_CUR + SZ_CUR;
static const size_t OFF_VST  = OFF_CUR5 + SZ_CUR5;
static const size_t OFF_CST  = OFF_VST + SZ_VST;
static const size_t OFF_CUR2 = OFF_CST + SZ_CST;             // split-K z=1 partials
static const size_t WS_NEED_SPLIT = OFF_CUR2 + SZ_CUR;

// ---------- prep: split fp32 W into hi/mid/lo bf16 planes ----------
__global__ void k_wsplit(const float* __restrict__ W, unsigned short* __restrict__ dst,
                         int nrows, int kvalid, int kpad) {
  int idx = blockIdx.x * blockDim.x + threadIdx.x;
  int kq = kvalid >> 2;
  if (idx >= nrows * kq) return;
  int row = idx / kq, k0 = (idx - row * kq) * 4;
  const float* src = W + (size_t)row * kvalid + k0;
  unsigned short h[4], m[4], l[4];
#pragma unroll
  for (int e = 0; e < 4; ++e) {
    float f = src[e];
    unsigned short hb = f2bf_rne(f);
    float r1 = f - bf2f(hb);
    unsigned short mb = f2bf_rne(r1);
    float r2 = r1 - bf2f(mb);
    unsigned short lb = f2bf_rne(r2);
    h[e] = hb; m[e] = mb; l[e] = lb;
  }
  size_t base = (size_t)row * kpad + k0;
  size_t plane = (size_t)nrows * kpad;
  *(ushort4*)(dst + base)             = make_ushort4(h[0], h[1], h[2], h[3]);
  *(ushort4*)(dst + plane + base)     = make_ushort4(m[0], m[1], m[2], m[3]);
  *(ushort4*)(dst + 2 * plane + base) = make_ushort4(l[0], l[1], l[2], l[3]);
}

__global__ void k_w4t(const float* __restrict__ W4, float* __restrict__ w4t) {
  int k = blockIdx.x * blockDim.x + threadIdx.x;
  if (k >= 2048) return;
#pragma unroll
  for (int c = 0; c < 16; ++c)
    w4t[(size_t)k * 16 + c] = (c < 10) ? W4[(size_t)c * 2048 + k] : 0.f;
}

// =====================================================================
// Main GEMM (phase-interleaved, early-issue staging, split-K x2)
// BM=256 BN=128 BK=32, 256 thr, 4 waves (2m x 2n), per-wave 128x64.
// LDS: dbuf x 40KB = 80KB -> 2 blocks/CU.
// Changes vs r4: (a) ALL 10 stage chunks issued at top of phase 0 ->
// ~3 phases of latency cover before the next head vmcnt(0) drain;
// (b) z-locked XCD map: z = xcd&1, each XCD owns an 8mt x 8nt quadrant
// of one K-half -> per-XCD distinct footprint 10.3 MB (vs 27 MB in r4).
// =====================================================================
__global__ __launch_bounds__(256, 2) void k_gemm3p(
    const unsigned short* __restrict__ A,   // [M][Ka] bf16 bits
    const unsigned short* __restrict__ B,   // [3][N][Ka] bf16 bits (W rows)
    float* __restrict__ C0,                 // z=0 partials [M][N]
    float* __restrict__ C1,                 // z=1 partials [M][N]
    int N, int Ka) {
  __shared__ unsigned short smem[2][20480]; // per buf: A[0,8192) | B s*4096 (128x32 each)
  const int tid = threadIdx.x;
  const int lane = tid & 63, wv = tid >> 6;

  // z-locked XCD map: bid = xcd + 8*lid; z = xcd&1; quadrant per xcd-pair
  const int bid = blockIdx.x;
  const int xcd = bid & 7, lid = bid >> 3;           // lid 0..63
  const int z  = xcd & 1;
  const int xg = xcd >> 1;                           // 0..3 quadrant
  const int mt = (xg >> 1) * 8 + (lid >> 3);         // 0..15
  const int nt = (xg & 1) * 8 + (lid & 7);           // 0..15
  const int m0 = mt * 256, n0 = nt * 128;
  const int Kh = Ka >> 1;                            // split-K half
  const int NT = Kh >> 5;
  const int koff0 = z * Kh;

  f32x4 acc[8][4];
#pragma unroll
  for (int i = 0; i < 8; ++i)
#pragma unroll
    for (int j = 0; j < 4; ++j) acc[i][j] = (f32x4){0.f, 0.f, 0.f, 0.f};

  // stage all 10 chunks of K-step kt into buf
  auto stage_all = [&](int buf, int kt) {
    const int koff = koff0 + kt * 32;
    const unsigned short* Abase = A + (size_t)m0 * Ka + koff;
#pragma unroll
    for (int i = 0; i < 10; ++i) {
      int c = i * 256 + tid;
      const unsigned short* src;
      if (c < 1024) {                        // A: 256 rows x 32k
        int row = c >> 2, kb = c & 3;
        int gkb = kb ^ ((row >> 1) & 3);     // source pre-swizzle (rule #21)
        src = Abase + (size_t)row * Ka + gkb * 8;
      } else {                               // B planes: 3 x (128 rows x 32k)
        int cb = c - 1024;
        int s = cb >> 9, cc = cb & 511;
        int row = cc >> 2, kb = cc & 3;
        int gkb = kb ^ ((row >> 1) & 3);
        src = B + ((size_t)s * N + n0 + row) * Ka + koff + gkb * 8;
      }
      gload_lds16(src, &smem[buf][(i * 256 + wv * 64) * 8]);
    }
  };

  const int wm = wv >> 1, wn = wv & 1;
  const int g = lane >> 4, rr = lane & 15;

  // prologue: stage step 0 fully
  stage_all(0, 0);

  for (int kt = 0; kt < NT; ++kt) {
    const int p = kt & 1;
    // ---- step head: ONLY correctness-critical sync ----
    asm volatile("s_waitcnt vmcnt(0)" ::: "memory");
    __builtin_amdgcn_sched_barrier(0);
    __builtin_amdgcn_s_barrier();
    __builtin_amdgcn_sched_barrier(0);

    // ---- early issue: ALL next-step loads go out first ----
    if (kt + 1 < NT) stage_all(p ^ 1, kt + 1);

    bf16x8 a[8];
#pragma unroll
    for (int mf = 0; mf < 8; ++mf) {
      int row = wm * 128 + mf * 16 + rr;
      int slot = g ^ ((row >> 1) & 3);
      a[mf] = *(const bf16x8*)&smem[p][row * 32 + slot * 8];
    }
#pragma unroll
    for (int s = 0; s < 3; ++s) {
      bf16x8 b[4];
#pragma unroll
      for (int nf = 0; nf < 4; ++nf) {
        int row = wn * 64 + nf * 16 + rr;
        int slot = g ^ ((row >> 1) & 3);
        b[nf] = *(const bf16x8*)&smem[p][8192 + s * 4096 + row * 32 + slot * 8];
      }
      __builtin_amdgcn_s_setprio(1);
#pragma unroll
      for (int mf = 0; mf < 8; ++mf)
#pragma unroll
        for (int nf = 0; nf < 4; ++nf)
          acc[mf][nf] = __builtin_amdgcn_mfma_f32_16x16x32_bf16(a[mf], b[nf], acc[mf][nf], 0, 0, 0);
      __builtin_amdgcn_s_setprio(0);
    }
  }

  float* __restrict__ Cz = z ? C1 : C0;
#pragma unroll
  for (int mf = 0; mf < 8; ++mf)
#pragma unroll
    for (int nf = 0; nf < 4; ++nf) {
      int col = n0 + wn * 64 + nf * 16 + rr;
#pragma unroll
      for (int v = 0; v < 4; ++v) {
        int row = m0 + wm * 128 + mf * 16 + g * 4 + v;  // D: row=(lane>>4)*4+reg, col=lane&15
        Cz[(size_t)row * N + col] = acc[mf][nf][v];
      }
    }
}

// ---------- fallback GEMM (round-3 proven path, used if ws too small) ----------
__global__ __launch_bounds__(256) void k_gemm3_old(
    const unsigned short* __restrict__ A, const unsigned short* __restrict__ B,
    float* __restrict__ C, int N, int Ka) {
  __shared__ unsigned short smem[2][16384];
  const int tid = threadIdx.x;
  const int lane = tid & 63, wv = tid >> 6;
  const int bid = blockIdx.x;
  const int xcd = bid & 7, lid = bid >> 3;
  const int by = (xcd >> 1) * 8 + (lid >> 3);
  const int bx = (xcd & 1) * 8 + (lid & 7);
  const int m0 = by * 128, n0 = bx * 128;
  const int NT = Ka >> 5;
  f32x4 acc[4][4];
#pragma unroll
  for (int i = 0; i < 4; ++i)
#pragma unroll
    for (int j = 0; j < 4; ++j) acc[i][j] = (f32x4){0.f, 0.f, 0.f, 0.f};
  auto stage = [&](int buf, int kk) {
    const unsigned short* Ab = A + (size_t)m0 * Ka + (size_t)kk * 32;
    const unsigned short* Bb = B + (size_t)n0 * Ka + (size_t)kk * 32;
#pragma unroll
    for (int i = 0; i < 8; ++i) {
      int chunk = wv * 64 + lane + i * 256;
      const unsigned short* src;
      if (i < 2) {
        int row = chunk >> 2, kb = chunk & 3;
        int gkb = kb ^ ((row >> 1) & 3);
        src = Ab + (size_t)row * Ka + gkb * 8;
      } else {
        int cb = chunk - 512;
        int s = cb >> 9, cc = cb & 511;
        int row = cc >> 2, kb = cc & 3;
        int gkb = kb ^ ((row >> 1) & 3);
        src = Bb + ((size_t)s * N + row) * Ka + gkb * 8;
      }
      gload_lds16(src, &smem[buf][i * 2048 + wv * 512]);
    }
  };
  const int wm = wv >> 1, wn = wv & 1;
  const int g = lane >> 4, rr = lane & 15;
  auto compute = [&](int buf) {
    bf16x8 a[4];
#pragma unroll
    for (int mf = 0; mf < 4; ++mf) {
      int row = wm * 64 + mf * 16 + rr;
      int slot = g ^ ((row >> 1) & 3);
      a[mf] = *(const bf16x8*)&smem[buf][row * 32 + slot * 8];
    }
#pragma unroll
    for (int s = 0; s < 3; ++s) {
      bf16x8 b[4];
#pragma unroll
      for (int nf = 0; nf < 4; ++nf) {
        int row = wn * 64 + nf * 16 + rr;
        int slot = g ^ ((row >> 1) & 3);
        b[nf] = *(const bf16x8*)&smem[buf][4096 + s * 4096 + row * 32 + slot * 8];
      }
#pragma unroll
      for (int mf = 0; mf < 4; ++mf)
#pragma unroll
        for (int nf = 0; nf < 4; ++nf)
          acc[mf][nf] = __builtin_amdgcn_mfma_f32_16x16x32_bf16(a[mf], b[nf], acc[mf][nf], 0, 0, 0);
    }
  };
  stage(0, 0);
  __syncthreads();
  for (int kt = 0; kt < NT; ++kt) {
    if (kt + 1 < NT) stage((kt + 1) & 1, kt + 1);
    compute(kt & 1);
    __syncthreads();
  }
#pragma unroll
  for (int mf = 0; mf < 4; ++mf)
#pragma unroll
    for (int nf = 0; nf < 4; ++nf) {
      int col = n0 + wn * 64 + nf * 16 + rr;
#pragma unroll
      for (int v = 0; v < 4; ++v) {
        int row = m0 + wm * 64 + mf * 16 + g * 4 + v;
        C[(size_t)row * N + col] = acc[mf][nf][v];
      }
    }
}

// ---------- LIF scans ----------
__global__ __launch_bounds__(128) void k_scan0(
    const float* __restrict__ input, unsigned short* __restrict__ spk0,
    float* __restrict__ vstats, int* __restrict__ cstats) {
  const int b = blockIdx.x, tid = threadIdx.x;
  const int j0 = tid * 8;
  const bool act = (j0 < NIN);
  const int lane = tid & 63, wv = tid >> 6;
  __shared__ float ssum[2][TSTEPS], ssq[2][TSTEPS];
  __shared__ int scnt[2][TSTEPS];
  float iv[8];
  if (act) {
    const float* ip = input + (size_t)b * NIN + j0;
    float4 c0 = *(const float4*)ip, c1 = *(const float4*)(ip + 4);
    iv[0]=c0.x; iv[1]=c0.y; iv[2]=c0.z; iv[3]=c0.w;
    iv[4]=c1.x; iv[5]=c1.y; iv[6]=c1.z; iv[7]=c1.w;
  } else {
#pragma unroll
    for (int e = 0; e < 8; ++e) iv[e] = 0.f;
  }
  float mem[8] = {0,0,0,0,0,0,0,0};
  for (int t = 0; t < TSTEPS; ++t) {
    float sum = 0.f, sq = 0.f; int cnt = 0;
    unsigned short sb[8];
#pragma unroll
    for (int e = 0; e < 8; ++e) {
      float reset = mem[e] > 1.0f ? 1.0f : 0.0f;
      float t1 = nofuse(BETA * mem[e]);
      float t2 = nofuse(t1 + iv[e]);
      float mn = t2 - reset;
      mem[e] = mn;
      int s = mn > 1.0f;
      sb[e] = s ? (unsigned short)0x3F80 : (unsigned short)0;
      sum += mn; sq = __fmaf_rn(mn, mn, sq); cnt += s;
    }
    if (act) {
      unsigned short* op = spk0 + (size_t)(t * BATCH + b) * KA0 + j0;
      *(ushort4*)op       = make_ushort4(sb[0], sb[1], sb[2], sb[3]);
      *(ushort4*)(op + 4) = make_ushort4(sb[4], sb[5], sb[6], sb[7]);
    }
#pragma unroll
    for (int o = 32; o > 0; o >>= 1) {
      sum += __shfl_down(sum, o, 64);
      sq  += __shfl_down(sq, o, 64);
      cnt += __shfl_down(cnt, o, 64);
    }
    if (lane == 0) { ssum[wv][t] = sum; ssq[wv][t] = sq; scnt[wv][t] = cnt; }
  }
  __syncthreads();
  if (tid < TSTEPS) {
    int t = tid;
    float s = ssum[0][t] + ssum[1][t];
    float q = ssq[0][t] + ssq[1][t];
    int c = scnt[0][t] + scnt[1][t];
    vstats[((size_t)(0 * TSTEPS + t) * 256 + b) * 2 + 0] = s;
    vstats[((size_t)(0 * TSTEPS + t) * 256 + b) * 2 + 1] = q;
    cstats[(0 * TSTEPS + t) * 256 + b] = c;
  }
}

// layers 1..4: cur = cur0 (+cur1 if parts==2) + bias -> LIF -> spk bf16
__global__ __launch_bounds__(128) void k_scan(
    const float* __restrict__ cur0, const float* __restrict__ cur1,
    const float* __restrict__ bias,
    unsigned short* __restrict__ spk, float* __restrict__ vstats,
    int* __restrict__ cstats, int layer, int parts) {
  const int blk = blockIdx.x;
  const int b = blk >> 1, half = blk & 1;
  const int tid = threadIdx.x;
  const int j0 = half * 1024 + tid * 8;
  const int lane = tid & 63, wv = tid >> 6;
  __shared__ float ssum[2][TSTEPS], ssq[2][TSTEPS];
  __shared__ int scnt[2][TSTEPS];
  float bs[8];
  {
    const float* bp = bias + j0;
    float4 c0 = *(const float4*)bp, c1 = *(const float4*)(bp + 4);
    bs[0]=c0.x; bs[1]=c0.y; bs[2]=c0.z; bs[3]=c0.w;
    bs[4]=c1.x; bs[5]=c1.y; bs[6]=c1.z; bs[7]=c1.w;
  }
  float mem[8] = {0,0,0,0,0,0,0,0};
  for (int t = 0; t < TSTEPS; ++t) {
    size_t off = (size_t)(t * BATCH + b) * 2048 + j0;
    const float* cp = cur0 + off;
    float4 c0 = *(const float4*)cp, c1 = *(const float4*)(cp + 4);
    float cv[8] = {c0.x, c0.y, c0.z, c0.w, c1.x, c1.y, c1.z, c1.w};
    if (parts == 2) {
      const float* cq = cur1 + off;
      float4 d0 = *(const float4*)cq, d1 = *(const float4*)(cq + 4);
      float dv[8] = {d0.x, d0.y, d0.z, d0.w, d1.x, d1.y, d1.z, d1.w};
#pragma unroll
      for (int e = 0; e < 8; ++e) cv[e] = nofuse(cv[e] + dv[e]);
    }
    float sum = 0.f, sq = 0.f; int cnt = 0;
    unsigned short sb[8];
#pragma unroll
    for (int e = 0; e < 8; ++e) {
      float cc = nofuse(cv[e] + bs[e]);
      float reset = mem[e] > 1.0f ? 1.0f : 0.0f;
      float t1 = nofuse(BETA * mem[e]);
      float t2 = nofuse(t1 + cc);
      float mn = t2 - reset;
      mem[e] = mn;
      int s = mn > 1.0f;
      sb[e] = s ? (unsigned short)0x3F80 : (unsigned short)0;
      sum += mn; sq = __fmaf_rn(mn, mn, sq); cnt += s;
    }
    unsigned short* op = spk + (size_t)(t * BATCH + b) * 2048 + j0;
    *(ushort4*)op       = make_ushort4(sb[0], sb[1], sb[2], sb[3]);
    *(ushort4*)(op + 4) = make_ushort4(sb[4], sb[5], sb[6], sb[7]);
#pragma unroll
    for (int o = 32; o > 0; o >>= 1) {
      sum += __shfl_down(sum, o, 64);
      sq  += __shfl_down(sq, o, 64);
      cnt += __shfl_down(cnt, o, 64);
    }
    if (lane == 0) { ssum[wv][t] = sum; ssq[wv][t] = sq; scnt[wv][t] = cnt; }
  }
  __syncthreads();
  if (tid < TSTEPS) {
    int t = tid;
    float s = ssum[0][t] + ssum[1][t];
    float q = ssq[0][t] + ssq[1][t];
    int c = scnt[0][t] + scnt[1][t];
    vstats[((size_t)(layer * TSTEPS + t) * 256 + blk) * 2 + 0] = s;
    vstats[((size_t)(layer * TSTEPS + t) * 256 + blk) * 2 + 1] = q;
    cstats[(layer * TSTEPS + t) * 256 + blk] = c;
  }
}

// small final GEMM: cur5[4096x16] = spk4 * W4t (fp32, exact per-dot fma)
__global__ __launch_bounds__(256) void k_gemm4(
    const unsigned short* __restrict__ spk, const float* __restrict__ w4t,
    float* __restrict__ out) {
  int idx = blockIdx.x * 256 + threadIdx.x;
  int r = idx >> 4, c = idx & 15;
  const unsigned short* sp = spk + (size_t)r * 2048;
  float acc = 0.f;
  for (int k = 0; k < 2048; k += 4) {
    ushort4 s4 = *(const ushort4*)(sp + k);
    acc = __fmaf_rn(bf2f(s4.x), w4t[(size_t)(k + 0) * 16 + c], acc);
    acc = __fmaf_rn(bf2f(s4.y), w4t[(size_t)(k + 1) * 16 + c], acc);
    acc = __fmaf_rn(bf2f(s4.z), w4t[(size_t)(k + 2) * 16 + c], acc);
    acc = __fmaf_rn(bf2f(s4.w), w4t[(size_t)(k + 3) * 16 + c], acc);
  }
  out[(size_t)r * 16 + c] = acc;
}

// layer 5: LIF over cur5, writes spike_out (d_out+5), counts only
__global__ __launch_bounds__(640) void k_scan5(
    const float* __restrict__ cur5, const float* __restrict__ b4,
    float* __restrict__ spike_out, int* __restrict__ cstats) {
  const int tid = threadIdx.x;
  const int idx = blockIdx.x * 640 + tid;
  const int b = idx / 10, j = idx - b * 10;
  const int lane = tid & 63, wv = tid >> 6;
  __shared__ int scnt[10][TSTEPS];
  const float bias = b4[j];
  float mem = 0.f;
  for (int t = 0; t < TSTEPS; ++t) {
    float cc = nofuse(cur5[(size_t)(t * BATCH + b) * 16 + j] + bias);
    float reset = mem > 1.0f ? 1.0f : 0.0f;
    float t1 = nofuse(BETA * mem);
    float t2 = nofuse(t1 + cc);
    float mn = t2 - reset;
    mem = mn;
    int s = mn > 1.0f;
    spike_out[(size_t)t * 1280 + b * 10 + j] = s ? 1.0f : 0.0f;
    int cnt = s;
#pragma unroll
    for (int o = 32; o > 0; o >>= 1) cnt += __shfl_down(cnt, o, 64);
    if (lane == 0) scnt[wv][t] = cnt;
  }
  __syncthreads();
  if (tid < TSTEPS) {
    int t = tid, c = 0;
#pragma unroll
    for (int w = 0; w < 10; ++w) c += scnt[w][t];
    cstats[(5 * TSTEPS + t) * 256 + blockIdx.x] = c;
  }
}

// final reduction
__global__ __launch_bounds__(512) void k_final(
    const float* __restrict__ vstats, const int* __restrict__ cstats,
    float* __restrict__ d_out) {
  __shared__ float varLDS[5][TSTEPS];
  __shared__ float cntLDS[6][TSTEPS];
  int tid = threadIdx.x;
  if (tid < 160) {
    int l = tid / 32, t = tid - l * 32;
    double s = 0.0, q = 0.0;
    for (int b = 0; b < 256; ++b) {
      s += (double)vstats[((size_t)(l * TSTEPS + t) * 256 + b) * 2 + 0];
      q += (double)vstats[((size_t)(l * TSTEPS + t) * 256 + b) * 2 + 1];
    }
    double n = (l == 0) ? (double)(BATCH * NIN) : (double)(BATCH * NHID);
    varLDS[l][t] = (float)((q - s * s / n) / (n - 1.0));
  } else if (tid < 352) {
    int i = (tid - 160) / 32, t = (tid - 160) - i * 32;
    int c = 0;
    for (int b = 0; b < 256; ++b) c += cstats[(i * TSTEPS + t) * 256 + b];
    cntLDS[i][t] = (float)c * (1.0f / 128.0f);
  }
  __syncthreads();
  if (tid < 5) {
    float a = 0.f;
    for (int t = 0; t < TSTEPS; ++t) a = __fadd_rn(a, varLDS[tid][t]);
    d_out[tid] = a / 32.0f;
  } else if (tid >= 8 && tid < 14) {
    int i = tid - 8;
    float a = 0.f;
    for (int t = 0; t < TSTEPS; ++t) a = __fadd_rn(a, cntLDS[i][t]);
    d_out[40965 + i] = a / 4096.0f;
  }
}

// ---------- launch ----------
extern "C" void kernel_launch(void* const* d_in, const int* in_sizes, int n_in,
                              void* d_out, int out_size, void* d_ws, size_t ws_size,
                              hipStream_t stream) {
  const float* input = (const float*)d_in[0];
  const float* W0 = (const float*)d_in[1];
  const float* W1 = (const float*)d_in[2];
  const float* W2 = (const float*)d_in[3];
  const float* W3 = (const float*)d_in[4];
  const float* W4 = (const float*)d_in[5];
  const float* b0 = (const float*)d_in[6];
  const float* b1 = (const float*)d_in[7];
  const float* b2 = (const float*)d_in[8];
  const float* b3 = (const float*)d_in[9];
  const float* b4 = (const float*)d_in[10];

  uint8_t* ws = (uint8_t*)d_ws;
  unsigned short* ws0  = (unsigned short*)(ws + OFF_WS0);
  unsigned short* ws1  = (unsigned short*)(ws + OFF_WS1);
  unsigned short* ws2  = (unsigned short*)(ws + OFF_WS2);
  unsigned short* ws3  = (unsigned short*)(ws + OFF_WS3);
  float* w4t           = (float*)(ws + OFF_W4T);
  unsigned short* spkA = (unsigned short*)(ws + OFF_SPKA);
  unsigned short* spkB = (unsigned short*)(ws + OFF_SPKB);
  float* cur           = (float*)(ws + OFF_CUR);
  float* cur2          = (float*)(ws + OFF_CUR2);
  float* cur5          = (float*)(ws + OFF_CUR5);
  float* vst           = (float*)(ws + OFF_VST);
  int* cst             = (int*)(ws + OFF_CST);
  float* out           = (float*)d_out;

  const bool split = (ws_size >= WS_NEED_SPLIT);

  hipMemsetAsync(ws + OFF_VST, 0, SZ_VST + SZ_CST, stream);
  hipMemsetAsync(ws + OFF_SPKA, 0, (size_t)TSTEPS * BATCH * KA0 * 2, stream);
  hipMemsetAsync(ws + OFF_WS0, 0, SZ_WS0, stream);

  {
    int thr = 2048 * (NIN / 4);
    k_wsplit<<<(thr + 255) / 256, 256, 0, stream>>>(W0, ws0, 2048, NIN, KA0);
  }
  {
    int thr = 2048 * (2048 / 4);
    int gb = (thr + 255) / 256;
    k_wsplit<<<gb, 256, 0, stream>>>(W1, ws1, 2048, 2048, 2048);
    k_wsplit<<<gb, 256, 0, stream>>>(W2, ws2, 2048, 2048, 2048);
    k_wsplit<<<gb, 256, 0, stream>>>(W3, ws3, 2048, 2048, 2048);
  }
  k_w4t<<<8, 256, 0, stream>>>(W4, w4t);

  k_scan0<<<BATCH, 128, 0, stream>>>(input, spkA, vst, cst);
  if (split) {
    k_gemm3p<<<512, 256, 0, stream>>>(spkA, ws0, cur, cur2, 2048, KA0);
    k_scan<<<256, 128, 0, stream>>>(cur, cur2, b0, spkB, vst, cst, 1, 2);
    k_gemm3p<<<512, 256, 0, stream>>>(spkB, ws1, cur, cur2, 2048, 2048);
    k_scan<<<256, 128, 0, stream>>>(cur, cur2, b1, spkA, vst, cst, 2, 2);
    k_gemm3p<<<512, 256, 0, stream>>>(spkA, ws2, cur, cur2, 2048, 2048);
    k_scan<<<256, 128, 0, stream>>>(cur, cur2, b2, spkB, vst, cst, 3, 2);
    k_gemm3p<<<512, 256, 0, stream>>>(spkB, ws3, cur, cur2, 2048, 2048);
    k_scan<<<256, 128, 0, stream>>>(cur, cur2, b3, spkA, vst, cst, 4, 2);
  } else {
    k_gemm3_old<<<512, 256, 0, stream>>>(spkA, ws0, cur, 2048, KA0);
    k_scan<<<256, 128, 0, stream>>>(cur, cur, b0, spkB, vst, cst, 1, 1);
    k_gemm3_old<<<512, 256, 0, stream>>>(spkB, ws1, cur, 2048, 2048);
    k_scan<<<256, 128, 0, stream>>>(cur, cur, b1, spkA, vst, cst, 2, 1);
    k_gemm3_old<<<512, 256, 0, stream>>>(spkA, ws2, cur, 2048, 2048);
    k_scan<<<256, 128, 0, stream>>>(cur, cur, b2, spkB, vst, cst, 3, 1);
    k_gemm3_old<<<512, 256, 0, stream>>>(spkB, ws3, cur, 2048, 2048);
    k_scan<<<256, 128, 0, stream>>>(cur, cur, b3, spkA, vst, cst, 4, 1);
  }
  k_gemm4<<<256, 256, 0, stream>>>(spkA, w4t, cur5);
  k_scan5<<<2, 640, 0, stream>>>(cur5, b4, out + 5, cst);
  k_final<<<1, 512, 0, stream>>>(vst, cst, out);
}

// Round 6
// 485.572 us; speedup vs baseline: 1.0978x; 1.0125x over previous
//
#include <hip/hip_runtime.h>
#include <stdint.h>

#define BETA 0.9f
#define NIN 784
#define KA0 832            // 784 padded to multiple of 32
#define NHID 2048
#define BATCH 128
#define TSTEPS 32
#define MROWS 4096         // 32*128

typedef __bf16 bf16x8 __attribute__((ext_vector_type(8)));
typedef float f32x4 __attribute__((ext_vector_type(4)));

// ---------- helpers ----------
__device__ __forceinline__ unsigned short f2bf_rne(float f) {
  union { float f; unsigned u; } v; v.f = f;
  unsigned u = v.u;
  return (unsigned short)((u + 0x7FFFu + ((u >> 16) & 1u)) >> 16);
}
__device__ __forceinline__ float bf2f(unsigned short b) {
  union { unsigned u; float f; } v; v.u = ((unsigned)b) << 16;
  return v.f;
}
__device__ __forceinline__ float nofuse(float x) {  // block fp-contraction
  asm volatile("" : "+v"(x));
  return x;
}

typedef __attribute__((address_space(1))) const unsigned int gas_uint;
typedef __attribute__((address_space(3))) unsigned int las_uint;
__device__ __forceinline__ void gload_lds16(const void* g, void* l) {
  __builtin_amdgcn_global_load_lds((gas_uint*)g, (las_uint*)l, 16, 0, 0);
}

// ---------- ws layout ----------
static const size_t SZ_WS0  = (size_t)3 * 2048 * KA0 * 2;    // W0 hi/mid/lo
static const size_t SZ_WSH  = (size_t)3 * 2048 * 2048 * 2;   // W1..W3
static const size_t SZ_W4T  = (size_t)2048 * 16 * 4;
static const size_t SZ_SPK  = (size_t)MROWS * 2048 * 2;
static const size_t SZ_CUR  = (size_t)MROWS * 2048 * 4;
static const size_t SZ_CUR5 = (size_t)MROWS * 16 * 4;
static const size_t SZ_VST  = (size_t)5 * TSTEPS * 256 * 2 * 4;
static const size_t SZ_CST  = (size_t)6 * TSTEPS * 256 * 4;

static const size_t OFF_WS0  = 0;
static const size_t OFF_WS1  = OFF_WS0 + SZ_WS0;
static const size_t OFF_WS2  = OFF_WS1 + SZ_WSH;
static const size_t OFF_WS3  = OFF_WS2 + SZ_WSH;
static const size_t OFF_W4T  = OFF_WS3 + SZ_WSH;
static const size_t OFF_SPKA = OFF_W4T + SZ_W4T;
static const size_t OFF_SPKB = OFF_SPKA + SZ_SPK;
static const size_t OFF_CUR  = OFF_SPKB + SZ_SPK;
static const size_t OFF_CUR5 = OFF_CUR + SZ_CUR;
static const size_t OFF_VST  = OFF_CUR5 + SZ_CUR5;
static const size_t OFF_CST  = OFF_VST + SZ_VST;
static const size_t OFF_CUR2 = OFF_CST + SZ_CST;             // split-K z=1 partials
static const size_t WS_NEED_SPLIT = OFF_CUR2 + SZ_CUR;

// ---------- prep: split fp32 W into hi/mid/lo bf16 planes ----------
__global__ void k_wsplit(const float* __restrict__ W, unsigned short* __restrict__ dst,
                         int nrows, int kvalid, int kpad) {
  int idx = blockIdx.x * blockDim.x + threadIdx.x;
  int kq = kvalid >> 2;
  if (idx >= nrows * kq) return;
  int row = idx / kq, k0 = (idx - row * kq) * 4;
  const float* src = W + (size_t)row * kvalid + k0;
  unsigned short h[4], m[4], l[4];
#pragma unroll
  for (int e = 0; e < 4; ++e) {
    float f = src[e];
    unsigned short hb = f2bf_rne(f);
    float r1 = f - bf2f(hb);
    unsigned short mb = f2bf_rne(r1);
    float r2 = r1 - bf2f(mb);
    unsigned short lb = f2bf_rne(r2);
    h[e] = hb; m[e] = mb; l[e] = lb;
  }
  size_t base = (size_t)row * kpad + k0;
  size_t plane = (size_t)nrows * kpad;
  *(ushort4*)(dst + base)             = make_ushort4(h[0], h[1], h[2], h[3]);
  *(ushort4*)(dst + plane + base)     = make_ushort4(m[0], m[1], m[2], m[3]);
  *(ushort4*)(dst + 2 * plane + base) = make_ushort4(l[0], l[1], l[2], l[3]);
}

__global__ void k_w4t(const float* __restrict__ W4, float* __restrict__ w4t) {
  int k = blockIdx.x * blockDim.x + threadIdx.x;
  if (k >= 2048) return;
#pragma unroll
  for (int c = 0; c < 16; ++c)
    w4t[(size_t)k * 16 + c] = (c < 10) ? W4[(size_t)c * 2048 + k] : 0.f;
}

// =====================================================================
// Main GEMM: phase-pipelined counted-vmcnt (T3+T4+T5), split-K x2.
// BM=256 BN=128 BK=32, 256 thr, 4 waves (2m x 2n), per-wave 128x64.
// LDS: dbuf x 40KB = 80KB -> 2 blocks/CU. z-locked XCD quadrant map.
// Per K-step, 3 plane-phases:
//   ph0: vmcnt(4)  barrier | issue next A(4)     | readA+readB0, 32 MFMA
//   ph1: vmcnt(6)  barrier | issue next B0,B1(4) | readB1, 32 MFMA
//   ph2: vmcnt(8)  barrier | issue next B2(2)    | readB2, 32 MFMA
// (epilogue step waits 4/2/0, no issue). Loads NEVER drain to 0 in loop.
// Issue order per stage: A(4),B0(2),B1(2),B2(2) -> vmcnt oldest-N math above.
// WAR on back buffer protected by ph0 barrier (step kt-1 reads all done).
// =====================================================================
__global__ __launch_bounds__(256, 2) void k_gemm3p(
    const unsigned short* __restrict__ A,   // [M][Ka] bf16 bits
    const unsigned short* __restrict__ B,   // [3][N][Ka] bf16 bits (W rows)
    float* __restrict__ C0,                 // z=0 partials [M][N]
    float* __restrict__ C1,                 // z=1 partials [M][N]
    int N, int Ka) {
  __shared__ unsigned short smem[2][20480]; // per buf: A[0,8192) | B s*4096
  const int tid = threadIdx.x;
  const int lane = tid & 63, wv = tid >> 6;

  // z-locked XCD map: z = xcd&1; xcd-pair owns an 8mt x 8nt quadrant
  const int bid = blockIdx.x;
  const int xcd = bid & 7, lid = bid >> 3;           // lid 0..63
  const int z  = xcd & 1;
  const int xg = xcd >> 1;                           // 0..3 quadrant
  const int mt = (xg >> 1) * 8 + (lid >> 3);         // 0..15
  const int nt = (xg & 1) * 8 + (lid & 7);           // 0..15
  const int m0 = mt * 256, n0 = nt * 128;
  const int Kh = Ka >> 1;                            // split-K half
  const int NT = Kh >> 5;
  const int koff0 = z * Kh;

  f32x4 acc[8][4];
#pragma unroll
  for (int i = 0; i < 8; ++i)
#pragma unroll
    for (int j = 0; j < 4; ++j) acc[i][j] = (f32x4){0.f, 0.f, 0.f, 0.f};

  // stage chunks [i0,i1) of K-step kt into buf. chunk map per thread:
  // i=0..3 -> A rows, i=4,5 -> B0, i=6,7 -> B1, i=8,9 -> B2
  auto stage_part = [&](int buf, int kt, int i0, int i1) {
    const int koff = koff0 + kt * 32;
    const unsigned short* Abase = A + (size_t)m0 * Ka + koff;
    for (int i = i0; i < i1; ++i) {
      int c = i * 256 + tid;
      const unsigned short* src;
      if (c < 1024) {                        // A: 256 rows x 32k
        int row = c >> 2, kb = c & 3;
        int gkb = kb ^ ((row >> 1) & 3);     // source pre-swizzle (rule #21)
        src = Abase + (size_t)row * Ka + gkb * 8;
      } else {                               // B planes: 3 x (128 rows x 32k)
        int cb = c - 1024;
        int s = cb >> 9, cc = cb & 511;
        int row = cc >> 2, kb = cc & 3;
        int gkb = kb ^ ((row >> 1) & 3);
        src = B + ((size_t)s * N + n0 + row) * Ka + koff + gkb * 8;
      }
      gload_lds16(src, &smem[buf][(i * 256 + wv * 64) * 8]);
    }
  };

  const int wm = wv >> 1, wn = wv & 1;
  const int g = lane >> 4, rr = lane & 15;

  auto readA = [&](int p, bf16x8* a) {
#pragma unroll
    for (int mf = 0; mf < 8; ++mf) {
      int row = wm * 128 + mf * 16 + rr;
      int slot = g ^ ((row >> 1) & 3);
      a[mf] = *(const bf16x8*)&smem[p][row * 32 + slot * 8];
    }
  };
  auto readB = [&](int p, int s, bf16x8* b) {
#pragma unroll
    for (int nf = 0; nf < 4; ++nf) {
      int row = wn * 64 + nf * 16 + rr;
      int slot = g ^ ((row >> 1) & 3);
      b[nf] = *(const bf16x8*)&smem[p][8192 + s * 4096 + row * 32 + slot * 8];
    }
  };
  auto cluster = [&](bf16x8* a, bf16x8* b) {
    __builtin_amdgcn_s_setprio(1);
#pragma unroll
    for (int mf = 0; mf < 8; ++mf)
#pragma unroll
      for (int nf = 0; nf < 4; ++nf)
        acc[mf][nf] = __builtin_amdgcn_mfma_f32_16x16x32_bf16(a[mf], b[nf], acc[mf][nf], 0, 0, 0);
    __builtin_amdgcn_s_setprio(0);
  };

#define PHASE_SYNC(nimm)                                   \
  asm volatile("s_waitcnt vmcnt(" #nimm ")" ::: "memory"); \
  __builtin_amdgcn_sched_barrier(0);                       \
  __builtin_amdgcn_s_barrier();                            \
  __builtin_amdgcn_sched_barrier(0);

  // prologue: stage step 0 fully (outstanding = 10)
  stage_part(0, 0, 0, 10);

  for (int kt = 0; kt < NT - 1; ++kt) {
    const int p = kt & 1;
    bf16x8 a[8], b[4];
    // ---- phase 0: A + B0 of kt ready; issue next A ----
    PHASE_SYNC(4)
    stage_part(p ^ 1, kt + 1, 0, 4);
    readA(p, a);
    readB(p, 0, b);
    cluster(a, b);
    // ---- phase 1: B1 of kt ready; issue next B0,B1 ----
    PHASE_SYNC(6)
    stage_part(p ^ 1, kt + 1, 4, 8);
    readB(p, 1, b);
    cluster(a, b);
    // ---- phase 2: B2 of kt ready; issue next B2 ----
    PHASE_SYNC(8)
    stage_part(p ^ 1, kt + 1, 8, 10);
    readB(p, 2, b);
    cluster(a, b);
  }
  { // epilogue step kt = NT-1 (no prefetch; waits 4/2/0)
    const int p = (NT - 1) & 1;
    bf16x8 a[8], b[4];
    PHASE_SYNC(4)
    readA(p, a);
    readB(p, 0, b);
    cluster(a, b);
    PHASE_SYNC(2)
    readB(p, 1, b);
    cluster(a, b);
    PHASE_SYNC(0)
    readB(p, 2, b);
    cluster(a, b);
  }
#undef PHASE_SYNC

  float* __restrict__ Cz = z ? C1 : C0;
#pragma unroll
  for (int mf = 0; mf < 8; ++mf)
#pragma unroll
    for (int nf = 0; nf < 4; ++nf) {
      int col = n0 + wn * 64 + nf * 16 + rr;
#pragma unroll
      for (int v = 0; v < 4; ++v) {
        int row = m0 + wm * 128 + mf * 16 + g * 4 + v;  // D: row=(lane>>4)*4+reg, col=lane&15
        Cz[(size_t)row * N + col] = acc[mf][nf][v];
      }
    }
}

// ---------- fallback GEMM (round-3 proven path, used if ws too small) ----------
__global__ __launch_bounds__(256) void k_gemm3_old(
    const unsigned short* __restrict__ A, const unsigned short* __restrict__ B,
    float* __restrict__ C, int N, int Ka) {
  __shared__ unsigned short smem[2][16384];
  const int tid = threadIdx.x;
  const int lane = tid & 63, wv = tid >> 6;
  const int bid = blockIdx.x;
  const int xcd = bid & 7, lid = bid >> 3;
  const int by = (xcd >> 1) * 8 + (lid >> 3);
  const int bx = (xcd & 1) * 8 + (lid & 7);
  const int m0 = by * 128, n0 = bx * 128;
  const int NT = Ka >> 5;
  f32x4 acc[4][4];
#pragma unroll
  for (int i = 0; i < 4; ++i)
#pragma unroll
    for (int j = 0; j < 4; ++j) acc[i][j] = (f32x4){0.f, 0.f, 0.f, 0.f};
  auto stage = [&](int buf, int kk) {
    const unsigned short* Ab = A + (size_t)m0 * Ka + (size_t)kk * 32;
    const unsigned short* Bb = B + (size_t)n0 * Ka + (size_t)kk * 32;
#pragma unroll
    for (int i = 0; i < 8; ++i) {
      int chunk = wv * 64 + lane + i * 256;
      const unsigned short* src;
      if (i < 2) {
        int row = chunk >> 2, kb = chunk & 3;
        int gkb = kb ^ ((row >> 1) & 3);
        src = Ab + (size_t)row * Ka + gkb * 8;
      } else {
        int cb = chunk - 512;
        int s = cb >> 9, cc = cb & 511;
        int row = cc >> 2, kb = cc & 3;
        int gkb = kb ^ ((row >> 1) & 3);
        src = Bb + ((size_t)s * N + row) * Ka + gkb * 8;
      }
      gload_lds16(src, &smem[buf][i * 2048 + wv * 512]);
    }
  };
  const int wm = wv >> 1, wn = wv & 1;
  const int g = lane >> 4, rr = lane & 15;
  auto compute = [&](int buf) {
    bf16x8 a[4];
#pragma unroll
    for (int mf = 0; mf < 4; ++mf) {
      int row = wm * 64 + mf * 16 + rr;
      int slot = g ^ ((row >> 1) & 3);
      a[mf] = *(const bf16x8*)&smem[buf][row * 32 + slot * 8];
    }
#pragma unroll
    for (int s = 0; s < 3; ++s) {
      bf16x8 b[4];
#pragma unroll
      for (int nf = 0; nf < 4; ++nf) {
        int row = wn * 64 + nf * 16 + rr;
        int slot = g ^ ((row >> 1) & 3);
        b[nf] = *(const bf16x8*)&smem[buf][4096 + s * 4096 + row * 32 + slot * 8];
      }
#pragma unroll
      for (int mf = 0; mf < 4; ++mf)
#pragma unroll
        for (int nf = 0; nf < 4; ++nf)
          acc[mf][nf] = __builtin_amdgcn_mfma_f32_16x16x32_bf16(a[mf], b[nf], acc[mf][nf], 0, 0, 0);
    }
  };
  stage(0, 0);
  __syncthreads();
  for (int kt = 0; kt < NT; ++kt) {
    if (kt + 1 < NT) stage((kt + 1) & 1, kt + 1);
    compute(kt & 1);
    __syncthreads();
  }
#pragma unroll
  for (int mf = 0; mf < 4; ++mf)
#pragma unroll
    for (int nf = 0; nf < 4; ++nf) {
      int col = n0 + wn * 64 + nf * 16 + rr;
#pragma unroll
      for (int v = 0; v < 4; ++v) {
        int row = m0 + wm * 64 + mf * 16 + g * 4 + v;
        C[(size_t)row * N + col] = acc[mf][nf][v];
      }
    }
}

// ---------- LIF scans ----------
__global__ __launch_bounds__(128) void k_scan0(
    const float* __restrict__ input, unsigned short* __restrict__ spk0,
    float* __restrict__ vstats, int* __restrict__ cstats) {
  const int b = blockIdx.x, tid = threadIdx.x;
  const int j0 = tid * 8;
  const bool act = (j0 < NIN);
  const int lane = tid & 63, wv = tid >> 6;
  __shared__ float ssum[2][TSTEPS], ssq[2][TSTEPS];
  __shared__ int scnt[2][TSTEPS];
  float iv[8];
  if (act) {
    const float* ip = input + (size_t)b * NIN + j0;
    float4 c0 = *(const float4*)ip, c1 = *(const float4*)(ip + 4);
    iv[0]=c0.x; iv[1]=c0.y; iv[2]=c0.z; iv[3]=c0.w;
    iv[4]=c1.x; iv[5]=c1.y; iv[6]=c1.z; iv[7]=c1.w;
  } else {
#pragma unroll
    for (int e = 0; e < 8; ++e) iv[e] = 0.f;
  }
  float mem[8] = {0,0,0,0,0,0,0,0};
  for (int t = 0; t < TSTEPS; ++t) {
    float sum = 0.f, sq = 0.f; int cnt = 0;
    unsigned short sb[8];
#pragma unroll
    for (int e = 0; e < 8; ++e) {
      float reset = mem[e] > 1.0f ? 1.0f : 0.0f;
      float t1 = nofuse(BETA * mem[e]);
      float t2 = nofuse(t1 + iv[e]);
      float mn = t2 - reset;
      mem[e] = mn;
      int s = mn > 1.0f;
      sb[e] = s ? (unsigned short)0x3F80 : (unsigned short)0;
      sum += mn; sq = __fmaf_rn(mn, mn, sq); cnt += s;
    }
    if (act) {
      unsigned short* op = spk0 + (size_t)(t * BATCH + b) * KA0 + j0;
      *(ushort4*)op       = make_ushort4(sb[0], sb[1], sb[2], sb[3]);
      *(ushort4*)(op + 4) = make_ushort4(sb[4], sb[5], sb[6], sb[7]);
    }
#pragma unroll
    for (int o = 32; o > 0; o >>= 1) {
      sum += __shfl_down(sum, o, 64);
      sq  += __shfl_down(sq, o, 64);
      cnt += __shfl_down(cnt, o, 64);
    }
    if (lane == 0) { ssum[wv][t] = sum; ssq[wv][t] = sq; scnt[wv][t] = cnt; }
  }
  __syncthreads();
  if (tid < TSTEPS) {
    int t = tid;
    float s = ssum[0][t] + ssum[1][t];
    float q = ssq[0][t] + ssq[1][t];
    int c = scnt[0][t] + scnt[1][t];
    vstats[((size_t)(0 * TSTEPS + t) * 256 + b) * 2 + 0] = s;
    vstats[((size_t)(0 * TSTEPS + t) * 256 + b) * 2 + 1] = q;
    cstats[(0 * TSTEPS + t) * 256 + b] = c;
  }
}

// layers 1..4: cur = cur0 (+cur1 if parts==2) + bias -> LIF -> spk bf16
__global__ __launch_bounds__(128) void k_scan(
    const float* __restrict__ cur0, const float* __restrict__ cur1,
    const float* __restrict__ bias,
    unsigned short* __restrict__ spk, float* __restrict__ vstats,
    int* __restrict__ cstats, int layer, int parts) {
  const int blk = blockIdx.x;
  const int b = blk >> 1, half = blk & 1;
  const int tid = threadIdx.x;
  const int j0 = half * 1024 + tid * 8;
  const int lane = tid & 63, wv = tid >> 6;
  __shared__ float ssum[2][TSTEPS], ssq[2][TSTEPS];
  __shared__ int scnt[2][TSTEPS];
  float bs[8];
  {
    const float* bp = bias + j0;
    float4 c0 = *(const float4*)bp, c1 = *(const float4*)(bp + 4);
    bs[0]=c0.x; bs[1]=c0.y; bs[2]=c0.z; bs[3]=c0.w;
    bs[4]=c1.x; bs[5]=c1.y; bs[6]=c1.z; bs[7]=c1.w;
  }
  float mem[8] = {0,0,0,0,0,0,0,0};
  for (int t = 0; t < TSTEPS; ++t) {
    size_t off = (size_t)(t * BATCH + b) * 2048 + j0;
    const float* cp = cur0 + off;
    float4 c0 = *(const float4*)cp, c1 = *(const float4*)(cp + 4);
    float cv[8] = {c0.x, c0.y, c0.z, c0.w, c1.x, c1.y, c1.z, c1.w};
    if (parts == 2) {
      const float* cq = cur1 + off;
      float4 d0 = *(const float4*)cq, d1 = *(const float4*)(cq + 4);
      float dv[8] = {d0.x, d0.y, d0.z, d0.w, d1.x, d1.y, d1.z, d1.w};
#pragma unroll
      for (int e = 0; e < 8; ++e) cv[e] = nofuse(cv[e] + dv[e]);
    }
    float sum = 0.f, sq = 0.f; int cnt = 0;
    unsigned short sb[8];
#pragma unroll
    for (int e = 0; e < 8; ++e) {
      float cc = nofuse(cv[e] + bs[e]);
      float reset = mem[e] > 1.0f ? 1.0f : 0.0f;
      float t1 = nofuse(BETA * mem[e]);
      float t2 = nofuse(t1 + cc);
      float mn = t2 - reset;
      mem[e] = mn;
      int s = mn > 1.0f;
      sb[e] = s ? (unsigned short)0x3F80 : (unsigned short)0;
      sum += mn; sq = __fmaf_rn(mn, mn, sq); cnt += s;
    }
    unsigned short* op = spk + (size_t)(t * BATCH + b) * 2048 + j0;
    *(ushort4*)op       = make_ushort4(sb[0], sb[1], sb[2], sb[3]);
    *(ushort4*)(op + 4) = make_ushort4(sb[4], sb[5], sb[6], sb[7]);
#pragma unroll
    for (int o = 32; o > 0; o >>= 1) {
      sum += __shfl_down(sum, o, 64);
      sq  += __shfl_down(sq, o, 64);
      cnt += __shfl_down(cnt, o, 64);
    }
    if (lane == 0) { ssum[wv][t] = sum; ssq[wv][t] = sq; scnt[wv][t] = cnt; }
  }
  __syncthreads();
  if (tid < TSTEPS) {
    int t = tid;
    float s = ssum[0][t] + ssum[1][t];
    float q = ssq[0][t] + ssq[1][t];
    int c = scnt[0][t] + scnt[1][t];
    vstats[((size_t)(layer * TSTEPS + t) * 256 + blk) * 2 + 0] = s;
    vstats[((size_t)(layer * TSTEPS + t) * 256 + blk) * 2 + 1] = q;
    cstats[(layer * TSTEPS + t) * 256 + blk] = c;
  }
}

// small final GEMM: cur5[4096x16] = spk4 * W4t (fp32, exact per-dot fma)
__global__ __launch_bounds__(256) void k_gemm4(
    const unsigned short* __restrict__ spk, const float* __restrict__ w4t,
    float* __restrict__ out) {
  int idx = blockIdx.x * 256 + threadIdx.x;
  int r = idx >> 4, c = idx & 15;
  const unsigned short* sp = spk + (size_t)r * 2048;
  float acc = 0.f;
  for (int k = 0; k < 2048; k += 4) {
    ushort4 s4 = *(const ushort4*)(sp + k);
    acc = __fmaf_rn(bf2f(s4.x), w4t[(size_t)(k + 0) * 16 + c], acc);
    acc = __fmaf_rn(bf2f(s4.y), w4t[(size_t)(k + 1) * 16 + c], acc);
    acc = __fmaf_rn(bf2f(s4.z), w4t[(size_t)(k + 2) * 16 + c], acc);
    acc = __fmaf_rn(bf2f(s4.w), w4t[(size_t)(k + 3) * 16 + c], acc);
  }
  out[(size_t)r * 16 + c] = acc;
}

// layer 5: LIF over cur5, writes spike_out (d_out+5), counts only
__global__ __launch_bounds__(640) void k_scan5(
    const float* __restrict__ cur5, const float* __restrict__ b4,
    float* __restrict__ spike_out, int* __restrict__ cstats) {
  const int tid = threadIdx.x;
  const int idx = blockIdx.x * 640 + tid;
  const int b = idx / 10, j = idx - b * 10;
  const int lane = tid & 63, wv = tid >> 6;
  __shared__ int scnt[10][TSTEPS];
  const float bias = b4[j];
  float mem = 0.f;
  for (int t = 0; t < TSTEPS; ++t) {
    float cc = nofuse(cur5[(size_t)(t * BATCH + b) * 16 + j] + bias);
    float reset = mem > 1.0f ? 1.0f : 0.0f;
    float t1 = nofuse(BETA * mem);
    float t2 = nofuse(t1 + cc);
    float mn = t2 - reset;
    mem = mn;
    int s = mn > 1.0f;
    spike_out[(size_t)t * 1280 + b * 10 + j] = s ? 1.0f : 0.0f;
    int cnt = s;
#pragma unroll
    for (int o = 32; o > 0; o >>= 1) cnt += __shfl_down(cnt, o, 64);
    if (lane == 0) scnt[wv][t] = cnt;
  }
  __syncthreads();
  if (tid < TSTEPS) {
    int t = tid, c = 0;
#pragma unroll
    for (int w = 0; w < 10; ++w) c += scnt[w][t];
    cstats[(5 * TSTEPS + t) * 256 + blockIdx.x] = c;
  }
}

// final reduction
__global__ __launch_bounds__(512) void k_final(
    const float* __restrict__ vstats, const int* __restrict__ cstats,
    float* __restrict__ d_out) {
  __shared__ float varLDS[5][TSTEPS];
  __shared__ float cntLDS[6][TSTEPS];
  int tid = threadIdx.x;
  if (tid < 160) {
    int l = tid / 32, t = tid - l * 32;
    double s = 0.0, q = 0.0;
    for (int b = 0; b < 256; ++b) {
      s += (double)vstats[((size_t)(l * TSTEPS + t) * 256 + b) * 2 + 0];
      q += (double)vstats[((size_t)(l * TSTEPS + t) * 256 + b) * 2 + 1];
    }
    double n = (l == 0) ? (double)(BATCH * NIN) : (double)(BATCH * NHID);
    varLDS[l][t] = (float)((q - s * s / n) / (n - 1.0));
  } else if (tid < 352) {
    int i = (tid - 160) / 32, t = (tid - 160) - i * 32;
    int c = 0;
    for (int b = 0; b < 256; ++b) c += cstats[(i * TSTEPS + t) * 256 + b];
    cntLDS[i][t] = (float)c * (1.0f / 128.0f);
  }
  __syncthreads();
  if (tid < 5) {
    float a = 0.f;
    for (int t = 0; t < TSTEPS; ++t) a = __fadd_rn(a, varLDS[tid][t]);
    d_out[tid] = a / 32.0f;
  } else if (tid >= 8 && tid < 14) {
    int i = tid - 8;
    float a = 0.f;
    for (int t = 0; t < TSTEPS; ++t) a = __fadd_rn(a, cntLDS[i][t]);
    d_out[40965 + i] = a / 4096.0f;
  }
}

// ---------- launch ----------
extern "C" void kernel_launch(void* const* d_in, const int* in_sizes, int n_in,
                              void* d_out, int out_size, void* d_ws, size_t ws_size,
                              hipStream_t stream) {
  const float* input = (const float*)d_in[0];
  const float* W0 = (const float*)d_in[1];
  const float* W1 = (const float*)d_in[2];
  const float* W2 = (const float*)d_in[3];
  const float* W3 = (const float*)d_in[4];
  const float* W4 = (const float*)d_in[5];
  const float* b0 = (const float*)d_in[6];
  const float* b1 = (const float*)d_in[7];
  const float* b2 = (const float*)d_in[8];
  const float* b3 = (const float*)d_in[9];
  const float* b4 = (const float*)d_in[10];

  uint8_t* ws = (uint8_t*)d_ws;
  unsigned short* ws0  = (unsigned short*)(ws + OFF_WS0);
  unsigned short* ws1  = (unsigned short*)(ws + OFF_WS1);
  unsigned short* ws2  = (unsigned short*)(ws + OFF_WS2);
  unsigned short* ws3  = (unsigned short*)(ws + OFF_WS3);
  float* w4t           = (float*)(ws + OFF_W4T);
  unsigned short* spkA = (unsigned short*)(ws + OFF_SPKA);
  unsigned short* spkB = (unsigned short*)(ws + OFF_SPKB);
  float* cur           = (float*)(ws + OFF_CUR);
  float* cur2          = (float*)(ws + OFF_CUR2);
  float* cur5          = (float*)(ws + OFF_CUR5);
  float* vst           = (float*)(ws + OFF_VST);
  int* cst             = (int*)(ws + OFF_CST);
  float* out           = (float*)d_out;

  const bool split = (ws_size >= WS_NEED_SPLIT);

  hipMemsetAsync(ws + OFF_VST, 0, SZ_VST + SZ_CST, stream);
  hipMemsetAsync(ws + OFF_SPKA, 0, (size_t)TSTEPS * BATCH * KA0 * 2, stream);
  hipMemsetAsync(ws + OFF_WS0, 0, SZ_WS0, stream);

  {
    int thr = 2048 * (NIN / 4);
    k_wsplit<<<(thr + 255) / 256, 256, 0, stream>>>(W0, ws0, 2048, NIN, KA0);
  }
  {
    int thr = 2048 * (2048 / 4);
    int gb = (thr + 255) / 256;
    k_wsplit<<<gb, 256, 0, stream>>>(W1, ws1, 2048, 2048, 2048);
    k_wsplit<<<gb, 256, 0, stream>>>(W2, ws2, 2048, 2048, 2048);
    k_wsplit<<<gb, 256, 0, stream>>>(W3, ws3, 2048, 2048, 2048);
  }
  k_w4t<<<8, 256, 0, stream>>>(W4, w4t);

  k_scan0<<<BATCH, 128, 0, stream>>>(input, spkA, vst, cst);
  if (split) {
    k_gemm3p<<<512, 256, 0, stream>>>(spkA, ws0, cur, cur2, 2048, KA0);
    k_scan<<<256, 128, 0, stream>>>(cur, cur2, b0, spkB, vst, cst, 1, 2);
    k_gemm3p<<<512, 256, 0, stream>>>(spkB, ws1, cur, cur2, 2048, 2048);
    k_scan<<<256, 128, 0, stream>>>(cur, cur2, b1, spkA, vst, cst, 2, 2);
    k_gemm3p<<<512, 256, 0, stream>>>(spkA, ws2, cur, cur2, 2048, 2048);
    k_scan<<<256, 128, 0, stream>>>(cur, cur2, b2, spkB, vst, cst, 3, 2);
    k_gemm3p<<<512, 256, 0, stream>>>(spkB, ws3, cur, cur2, 2048, 2048);
    k_scan<<<256, 128, 0, stream>>>(cur, cur2, b3, spkA, vst, cst, 4, 2);
  } else {
    k_gemm3_old<<<512, 256, 0, stream>>>(spkA, ws0, cur, 2048, KA0);
    k_scan<<<256, 128, 0, stream>>>(cur, cur, b0, spkB, vst, cst, 1, 1);
    k_gemm3_old<<<512, 256, 0, stream>>>(spkB, ws1, cur, 2048, 2048);
    k_scan<<<256, 128, 0, stream>>>(cur, cur, b1, spkA, vst, cst, 2, 1);
    k_gemm3_old<<<512, 256, 0, stream>>>(spkA, ws2, cur, 2048, 2048);
    k_scan<<<256, 128, 0, stream>>>(cur, cur, b2, spkB, vst, cst, 3, 1);
    k_gemm3_old<<<512, 256, 0, stream>>>(spkB, ws3, cur, 2048, 2048);
    k_scan<<<256, 128, 0, stream>>>(cur, cur, b3, spkA, vst, cst, 4, 1);
  }
  k_gemm4<<<256, 256, 0, stream>>>(spkA, w4t, cur5);
  k_scan5<<<2, 640, 0, stream>>>(cur5, b4, out + 5, cst);
  k_final<<<1, 512, 0, stream>>>(vst, cst, out);
}